// Round 5
// baseline (365.944 us; speedup 1.0000x reference)
//
#include <hip/hip_runtime.h>

#define RES 8
#define F 512      // RES^3
#define CLASSES 40
#define B 64
#define NPTS 100000

#define MM_BLOCKS 48   // per batch; 48*256 % 3 == 0 (component-phase invariant)
#define H_BLOCKS 32    // per batch

// ws layout (4-byte units), all write-before-read (no init kernel):
// PARTH : B * H_BLOCKS * F uints   — per-block partial histograms (4 MB)
// PARTMM: B * MM_BLOCKS * 6 floats — per-block partial min(0..2)/max(3..5)
// CNT   : B uints                  — hist-done counters (zeroed by minmax_kernel)
#define PARTH_OFF 0
#define PARTMM_OFF (B * H_BLOCKS * F)
#define CNT_OFF (PARTMM_OFF + B * MM_BLOCKS * 6)

// Per batch: 75000 float4s. Thread's float4-index stride = MM_BLOCKS*256
// (multiple of 3) -> component phase c0 = idx%3 fixed per thread. For float4
// idx i, components are (i, i+1, i+2, i) mod 3:
//   m0 <- {e.x, e.w} (comp c0), m1 <- e.y (c0+1), m2 <- e.z (c0+2).
__global__ __launch_bounds__(256) void minmax_kernel(const float* __restrict__ x,
                                                     unsigned int* __restrict__ ws) {
    const int batch = blockIdx.y;
    const float4* xb4 = (const float4*)(x + (size_t)batch * (NPTS * 3));
    const int t = threadIdx.x;
    const int NF4 = NPTS * 3 / 4;          // 75000
    const int stride = MM_BLOCKS * 256;    // 12288, % 3 == 0

    // zero this batch's hist-done counter (stream-orders before hist_kernel)
    if (blockIdx.x == 0 && t == 64) ws[CNT_OFF + batch] = 0u;

    float m0 = 3.0e38f, m1 = 3.0e38f, m2 = 3.0e38f;
    float M0 = -3.0e38f, M1 = -3.0e38f, M2 = -3.0e38f;
    for (int i = blockIdx.x * 256 + t; i < NF4; i += stride) {
        float4 e = xb4[i];
        m0 = fminf(m0, fminf(e.x, e.w));  M0 = fmaxf(M0, fmaxf(e.x, e.w));
        m1 = fminf(m1, e.y);              M1 = fmaxf(M1, e.y);
        m2 = fminf(m2, e.z);              M2 = fmaxf(M2, e.z);
    }

    // Rotate to absolute components.
    const int c0 = (blockIdx.x * 256 + t) % 3;
    float a0, a1, a2, A0, A1, A2;
    if (c0 == 0)      { a0 = m0; a1 = m1; a2 = m2; A0 = M0; A1 = M1; A2 = M2; }
    else if (c0 == 1) { a0 = m2; a1 = m0; a2 = m1; A0 = M2; A1 = M0; A2 = M1; }
    else              { a0 = m1; a1 = m2; a2 = m0; A0 = M1; A1 = M2; A2 = M0; }

    for (int d = 1; d < 64; d <<= 1) {
        a0 = fminf(a0, __shfl_xor(a0, d)); A0 = fmaxf(A0, __shfl_xor(A0, d));
        a1 = fminf(a1, __shfl_xor(a1, d)); A1 = fmaxf(A1, __shfl_xor(A1, d));
        a2 = fminf(a2, __shfl_xor(a2, d)); A2 = fmaxf(A2, __shfl_xor(A2, d));
    }

    __shared__ float wmin[4][3], wmax[4][3];
    const int wave = t >> 6;
    if ((t & 63) == 0) {
        wmin[wave][0] = a0; wmin[wave][1] = a1; wmin[wave][2] = a2;
        wmax[wave][0] = A0; wmax[wave][1] = A1; wmax[wave][2] = A2;
    }
    __syncthreads();
    if (t < 3) {
        float mn = fminf(fminf(wmin[0][t], wmin[1][t]), fminf(wmin[2][t], wmin[3][t]));
        float mx = fmaxf(fmaxf(wmax[0][t], wmax[1][t]), fmaxf(wmax[2][t], wmax[3][t]));
        float* pm = (float*)(ws + PARTMM_OFF) + ((size_t)batch * MM_BLOCKS + blockIdx.x) * 6;
        pm[t] = mn;
        pm[3 + t] = mx;
    }
}

// Reduce 48 min/max partials in-block, per-wave LDS sub-histograms, write this
// block's 512-bin partial. The LAST finishing block per batch (fence+counter,
// no spin -> deadlock-free without co-residency) reduces the 32 partials and
// computes the batch's logits.
__global__ __launch_bounds__(256) void hist_kernel(const float* __restrict__ x,
                                                   const float* __restrict__ Wm,
                                                   const float* __restrict__ bias,
                                                   float* __restrict__ out,
                                                   unsigned int* __restrict__ ws) {
    const int batch = blockIdx.y;
    const int t = threadIdx.x;

    __shared__ unsigned int lh[4][F];   // per-wave sub-histograms (8 KB)
    __shared__ float red[6][16];
    __shared__ float smn[3], ssc[3];
    __shared__ unsigned int lastFlag;

    for (int i = t; i < 4 * F; i += 256) ((unsigned int*)lh)[i] = 0u;

    const float* pm = (const float*)(ws + PARTMM_OFF) + (size_t)batch * MM_BLOCKS * 6;
    if (t < 96) {                       // c = t%6, j0 = t/6 in [0,16)
        const int c = t % 6, j0 = t / 6;
        float v0 = pm[(j0 +  0) * 6 + c];
        float v1 = pm[(j0 + 16) * 6 + c];
        float v2 = pm[(j0 + 32) * 6 + c];
        red[c][j0] = (c < 3) ? fminf(v0, fminf(v1, v2)) : fmaxf(v0, fmaxf(v1, v2));
    }
    __syncthreads();
    if (t < 3) {
        float mn = red[t][0], mx = red[t + 3][0];
#pragma unroll
        for (int j = 1; j < 16; ++j) {
            mn = fminf(mn, red[t][j]);
            mx = fmaxf(mx, red[t + 3][j]);
        }
        float rng = mx - mn;
        smn[t] = mn;
        ssc[t] = (float)RES / (rng > 0.0f ? rng : 1.0f);  // same fp32 div as ref
    }
    __syncthreads();

    const float mn0 = smn[0], mn1 = smn[1], mn2 = smn[2];
    const float sc0 = ssc[0], sc1 = ssc[1], sc2 = ssc[2];
    const float4* xb4 = (const float4*)(x + (size_t)batch * (NPTS * 3));
    unsigned int* myh = lh[t >> 6];

    const int NSLOT = NPTS / 4;  // 25000; each slot = 4 points = 3 float4 loads
    for (int i = blockIdx.x * 256 + t; i < NSLOT; i += H_BLOCKS * 256) {
        float4 p0 = xb4[3 * i + 0];
        float4 p1 = xb4[3 * i + 1];
        float4 p2 = xb4[3 * i + 2];
        float px[4][3] = {{p0.x, p0.y, p0.z},
                          {p0.w, p1.x, p1.y},
                          {p1.z, p1.w, p2.x},
                          {p2.y, p2.z, p2.w}};
#pragma unroll
        for (int q = 0; q < 4; ++q) {
            int i0 = (int)floorf((px[q][0] - mn0) * sc0);
            int i1 = (int)floorf((px[q][1] - mn1) * sc1);
            int i2 = (int)floorf((px[q][2] - mn2) * sc2);
            i0 = min(max(i0, 0), RES - 1);
            i1 = min(max(i1, 0), RES - 1);
            i2 = min(max(i2, 0), RES - 1);
            atomicAdd(&myh[(i0 * RES + i1) * RES + i2], 1u);
        }
    }
    __syncthreads();

    unsigned int* ph = ws + PARTH_OFF + ((size_t)batch * H_BLOCKS + blockIdx.x) * F;
    for (int bin = t; bin < F; bin += 256)
        ph[bin] = lh[0][bin] + lh[1][bin] + lh[2][bin] + lh[3][bin];

    // ---- finalization: last block per batch does the logits ----
    __threadfence();                      // make our partial visible device-wide
    __syncthreads();                      // all threads' stores fenced
    if (t == 0)
        lastFlag = (atomicAdd(&ws[CNT_OFF + batch], 1u) == H_BLOCKS - 1) ? 1u : 0u;
    __syncthreads();
    if (lastFlag) {
        __threadfence();                  // acquire: see all blocks' partials
        const unsigned int* phb = ws + PARTH_OFF + (size_t)batch * H_BLOCKS * F;
        float* cf = (float*)lh[0];        // reuse LDS
        for (int bin = t; bin < F; bin += 256) {
            unsigned int s = 0;
#pragma unroll
            for (int j = 0; j < H_BLOCKS; ++j) s += phb[j * F + bin];
            cf[bin] = (float)s * (1.0f / (float)NPTS);
        }
        __syncthreads();
        if (t < CLASSES) {
            const float4* wr = (const float4*)(Wm + t * F);
            const float4* cf4 = (const float4*)cf;
            float d0 = 0.f, d1 = 0.f, d2 = 0.f, d3 = 0.f;
#pragma unroll 4
            for (int k = 0; k < F / 4; k += 4) {
                float4 w0 = wr[k],   c0 = cf4[k];
                float4 w1 = wr[k+1], c1 = cf4[k+1];
                float4 w2 = wr[k+2], c2 = cf4[k+2];
                float4 w3 = wr[k+3], c3 = cf4[k+3];
                d0 += c0.x*w0.x + c0.y*w0.y + c0.z*w0.z + c0.w*w0.w;
                d1 += c1.x*w1.x + c1.y*w1.y + c1.z*w1.z + c1.w*w1.w;
                d2 += c2.x*w2.x + c2.y*w2.y + c2.z*w2.z + c2.w*w2.w;
                d3 += c3.x*w3.x + c3.y*w3.y + c3.z*w3.z + c3.w*w3.w;
            }
            out[batch * CLASSES + t] = ((d0 + d1) + (d2 + d3)) + bias[t];
        }
    }
}

extern "C" void kernel_launch(void* const* d_in, const int* in_sizes, int n_in,
                              void* d_out, int out_size, void* d_ws, size_t ws_size,
                              hipStream_t stream) {
    const float* x    = (const float*)d_in[0];
    const float* Wm   = (const float*)d_in[1];
    const float* bias = (const float*)d_in[2];
    float* out        = (float*)d_out;
    unsigned int* ws  = (unsigned int*)d_ws;

    minmax_kernel<<<dim3(MM_BLOCKS, B), 256, 0, stream>>>(x, ws);
    hist_kernel<<<dim3(H_BLOCKS, B), 256, 0, stream>>>(x, Wm, bias, out, ws);
}

// Round 6
// 130.128 us; speedup vs baseline: 2.8122x; 2.8122x over previous
//
#include <hip/hip_runtime.h>

#define RES 8
#define F 512      // RES^3
#define CLASSES 40
#define B 64
#define NPTS 100000

#define MM_BLOCKS 48   // per batch; 48*256 % 3 == 0 (component-phase invariant)
#define H_BLOCKS 32    // per batch

// ws layout (4-byte units). Everything is write-before-read; no init kernel.
// PARTH : B * H_BLOCKS * F uints      — per-block partial histograms (4 MB)
// PARTMM: B * MM_BLOCKS * 6 floats    — per-block partial min(0..2)/max(3..5)
#define PARTH_OFF 0
#define PARTMM_OFF (B * H_BLOCKS * F)

// Per batch: 75000 float4s (300000 floats). Thread's float4-index stride =
// MM_BLOCKS*256 (multiple of 3) -> component phase c0 = idx%3 fixed per
// thread. For float4 idx i, components are (i, i+1, i+2, i) mod 3:
//   m0 <- {e.x, e.w} (comp c0), m1 <- e.y (c0+1), m2 <- e.z (c0+2).
__global__ __launch_bounds__(256) void minmax_kernel(const float* __restrict__ x,
                                                     unsigned int* __restrict__ ws) {
    const int batch = blockIdx.y;
    const float4* xb4 = (const float4*)(x + (size_t)batch * (NPTS * 3));
    const int t = threadIdx.x;
    const int NF4 = NPTS * 3 / 4;          // 75000
    const int stride = MM_BLOCKS * 256;    // 12288, % 3 == 0

    float m0 = 3.0e38f, m1 = 3.0e38f, m2 = 3.0e38f;
    float M0 = -3.0e38f, M1 = -3.0e38f, M2 = -3.0e38f;
    for (int i = blockIdx.x * 256 + t; i < NF4; i += stride) {
        float4 e = xb4[i];
        m0 = fminf(m0, fminf(e.x, e.w));  M0 = fmaxf(M0, fmaxf(e.x, e.w));
        m1 = fminf(m1, e.y);              M1 = fmaxf(M1, e.y);
        m2 = fminf(m2, e.z);              M2 = fmaxf(M2, e.z);
    }

    // Rotate to absolute components.
    const int c0 = (blockIdx.x * 256 + t) % 3;
    float a0, a1, a2, A0, A1, A2;
    if (c0 == 0)      { a0 = m0; a1 = m1; a2 = m2; A0 = M0; A1 = M1; A2 = M2; }
    else if (c0 == 1) { a0 = m2; a1 = m0; a2 = m1; A0 = M2; A1 = M0; A2 = M1; }
    else              { a0 = m1; a1 = m2; a2 = m0; A0 = M1; A1 = M2; A2 = M0; }

    for (int d = 1; d < 64; d <<= 1) {
        a0 = fminf(a0, __shfl_xor(a0, d)); A0 = fmaxf(A0, __shfl_xor(A0, d));
        a1 = fminf(a1, __shfl_xor(a1, d)); A1 = fmaxf(A1, __shfl_xor(A1, d));
        a2 = fminf(a2, __shfl_xor(a2, d)); A2 = fmaxf(A2, __shfl_xor(A2, d));
    }

    __shared__ float wmin[4][3], wmax[4][3];
    const int wave = t >> 6;
    if ((t & 63) == 0) {
        wmin[wave][0] = a0; wmin[wave][1] = a1; wmin[wave][2] = a2;
        wmax[wave][0] = A0; wmax[wave][1] = A1; wmax[wave][2] = A2;
    }
    __syncthreads();
    if (t < 3) {
        float mn = fminf(fminf(wmin[0][t], wmin[1][t]), fminf(wmin[2][t], wmin[3][t]));
        float mx = fmaxf(fmaxf(wmax[0][t], wmax[1][t]), fmaxf(wmax[2][t], wmax[3][t]));
        float* pm = (float*)(ws + PARTMM_OFF) + ((size_t)batch * MM_BLOCKS + blockIdx.x) * 6;
        pm[t] = mn;
        pm[3 + t] = mx;
    }
}

// Reduce 48 min/max partials in-block, then per-wave LDS sub-histograms,
// then write this block's 512-bin partial histogram (write-only, no atomics).
__global__ __launch_bounds__(256) void hist_kernel(const float* __restrict__ x,
                                                   unsigned int* __restrict__ ws) {
    const int batch = blockIdx.y;
    const int t = threadIdx.x;

    __shared__ unsigned int lh[4][F];   // one sub-histogram per wave (8 KB)
    __shared__ float red[6][16];
    __shared__ float smn[3], ssc[3];

    for (int i = t; i < 4 * F; i += 256) ((unsigned int*)lh)[i] = 0u;

    const float* pm = (const float*)(ws + PARTMM_OFF) + (size_t)batch * MM_BLOCKS * 6;
    if (t < 96) {                       // c = t%6, j0 = t/6 in [0,16)
        const int c = t % 6, j0 = t / 6;
        float v0 = pm[(j0 +  0) * 6 + c];
        float v1 = pm[(j0 + 16) * 6 + c];
        float v2 = pm[(j0 + 32) * 6 + c];
        red[c][j0] = (c < 3) ? fminf(v0, fminf(v1, v2)) : fmaxf(v0, fmaxf(v1, v2));
    }
    __syncthreads();
    if (t < 3) {
        float mn = red[t][0], mx = red[t + 3][0];
#pragma unroll
        for (int j = 1; j < 16; ++j) {
            mn = fminf(mn, red[t][j]);
            mx = fmaxf(mx, red[t + 3][j]);
        }
        float rng = mx - mn;
        smn[t] = mn;
        ssc[t] = (float)RES / (rng > 0.0f ? rng : 1.0f);  // same fp32 div as ref
    }
    __syncthreads();

    const float mn0 = smn[0], mn1 = smn[1], mn2 = smn[2];
    const float sc0 = ssc[0], sc1 = ssc[1], sc2 = ssc[2];
    const float4* xb4 = (const float4*)(x + (size_t)batch * (NPTS * 3));
    unsigned int* myh = lh[t >> 6];

    const int NSLOT = NPTS / 4;  // 25000; each slot = 4 points = 3 float4 loads
    for (int i = blockIdx.x * 256 + t; i < NSLOT; i += H_BLOCKS * 256) {
        float4 p0 = xb4[3 * i + 0];
        float4 p1 = xb4[3 * i + 1];
        float4 p2 = xb4[3 * i + 2];
        float px[4][3] = {{p0.x, p0.y, p0.z},
                          {p0.w, p1.x, p1.y},
                          {p1.z, p1.w, p2.x},
                          {p2.y, p2.z, p2.w}};
#pragma unroll
        for (int q = 0; q < 4; ++q) {
            int i0 = (int)floorf((px[q][0] - mn0) * sc0);
            int i1 = (int)floorf((px[q][1] - mn1) * sc1);
            int i2 = (int)floorf((px[q][2] - mn2) * sc2);
            i0 = min(max(i0, 0), RES - 1);
            i1 = min(max(i1, 0), RES - 1);
            i2 = min(max(i2, 0), RES - 1);
            atomicAdd(&myh[(i0 * RES + i1) * RES + i2], 1u);
        }
    }
    __syncthreads();

    unsigned int* ph = ws + PARTH_OFF + ((size_t)batch * H_BLOCKS + blockIdx.x) * F;
    for (int bin = t; bin < F; bin += 256)
        ph[bin] = lh[0][bin] + lh[1][bin] + lh[2][bin] + lh[3][bin];
}

__global__ __launch_bounds__(256) void logits_kernel(const unsigned int* __restrict__ ws,
                                                     const float* __restrict__ Wm,
                                                     const float* __restrict__ bias,
                                                     float* __restrict__ out) {
    const int batch = blockIdx.x;
    const int t = threadIdx.x;
    __shared__ float cf[F];
    const unsigned int* ph = ws + PARTH_OFF + (size_t)batch * H_BLOCKS * F;
    for (int bin = t; bin < F; bin += 256) {
        unsigned int s = 0;
#pragma unroll
        for (int j = 0; j < H_BLOCKS; ++j) s += ph[j * F + bin];
        cf[bin] = (float)s * (1.0f / (float)NPTS);
    }
    __syncthreads();
    if (t < CLASSES) {
        const float4* wr = (const float4*)(Wm + t * F);
        const float4* cf4 = (const float4*)cf;
        float d0 = 0.f, d1 = 0.f, d2 = 0.f, d3 = 0.f;
#pragma unroll 4
        for (int k = 0; k < F / 4; k += 4) {
            float4 w0 = wr[k], c0 = cf4[k];
            float4 w1 = wr[k+1], c1 = cf4[k+1];
            float4 w2 = wr[k+2], c2 = cf4[k+2];
            float4 w3 = wr[k+3], c3 = cf4[k+3];
            d0 += c0.x*w0.x + c0.y*w0.y + c0.z*w0.z + c0.w*w0.w;
            d1 += c1.x*w1.x + c1.y*w1.y + c1.z*w1.z + c1.w*w1.w;
            d2 += c2.x*w2.x + c2.y*w2.y + c2.z*w2.z + c2.w*w2.w;
            d3 += c3.x*w3.x + c3.y*w3.y + c3.z*w3.z + c3.w*w3.w;
        }
        out[batch * CLASSES + t] = ((d0 + d1) + (d2 + d3)) + bias[t];
    }
}

extern "C" void kernel_launch(void* const* d_in, const int* in_sizes, int n_in,
                              void* d_out, int out_size, void* d_ws, size_t ws_size,
                              hipStream_t stream) {
    const float* x    = (const float*)d_in[0];
    const float* Wm   = (const float*)d_in[1];
    const float* bias = (const float*)d_in[2];
    float* out        = (float*)d_out;
    unsigned int* ws  = (unsigned int*)d_ws;

    minmax_kernel<<<dim3(MM_BLOCKS, B), 256, 0, stream>>>(x, ws);
    hist_kernel<<<dim3(H_BLOCKS, B), 256, 0, stream>>>(x, ws);
    logits_kernel<<<B, 256, 0, stream>>>(ws, Wm, bias, out);
}